// Round 3
// baseline (313.713 us; speedup 1.0000x reference)
//
#include <hip/hip_runtime.h>
#include <hip/hip_bf16.h>
#include <hip/hip_fp16.h>
#include <math.h>

// Problem constants (B,S,H,M) = (8,128,768,128)
#define B_   8
#define S_   128
#define H_   768
#define M_   128
#define P_   8256      // S*(S+1)/2 pairs per batch
#define BP_  66048     // B_ * P_
#define EPSF 1e-12f

typedef unsigned short u16;
typedef unsigned int   u32;
typedef _Float16 h16;
typedef _Float16 ffrag __attribute__((ext_vector_type(8)));   // 8 f16 = 4 VGPR
typedef float    f32x4 __attribute__((ext_vector_type(4)));

__device__ __forceinline__ u32 mul2(u32 x, u32 g) {
    __half2 r = __hmul2(__builtin_bit_cast(__half2, x), __builtin_bit_cast(__half2, g));
    return __builtin_bit_cast(u32, r);
}
__device__ __forceinline__ float fast_tanh(float v) {
    float e = __expf(-2.0f * fabsf(v));
    float t = (1.0f - e) / (1.0f + e);
    return copysignf(t, v);
}

// ============ kernel 0: convert weights to f16; build WcT[n][h]; biasc ============
__global__ void k_convert(const float* __restrict__ wg, const float* __restrict__ wb,
                          const float* __restrict__ we, const float* __restrict__ wh,
                          const float* __restrict__ wt,
                          const float* __restrict__ be, const float* __restrict__ bh,
                          const float* __restrict__ bt,
                          h16* __restrict__ wgb, h16* __restrict__ wbb,
                          h16* __restrict__ wct, float* __restrict__ biasc)
{
    int idx = blockIdx.x * 256 + threadIdx.x;
    if (idx < 589824) {
        wgb[idx] = (h16)wg[idx];
    } else if (idx < 1179648) {
        int i = idx - 589824;
        wbb[i] = (h16)wb[i];
    } else if (idx < 1474560) {
        int i = idx - 1179648;              // [0, 294912) : n in [0,384), h in [0,768)
        int n = i / 768, h = i - n * 768;
        const float* w = (n < 128) ? we : (n < 256 ? wh : wt);
        wct[i] = (h16)w[h * 128 + (n & 127)];
    } else if (idx < 1474944) {
        int n = idx - 1474560;              // [0,384)
        biasc[n] = (n < 128) ? be[n] : (n < 256 ? bh[n - 128] : bt[n - 256]);
    }
}

// ============ kernel 1: per-row normalize + seq->f16 ============
// xn[row] = (x - mean) / (var + eps)^2   (reference squares, no sqrt!)
__global__ void k_norm(const float* __restrict__ seq, h16* __restrict__ xn, h16* __restrict__ condb)
{
    __shared__ float red[4];
    const int row = blockIdx.x;
    const int t = threadIdx.x;
    const int lane = t & 63, wid = t >> 6;
    const float* x = seq + (size_t)row * H_;
    float x0 = x[t], x1 = x[t + 256], x2 = x[t + 512];

    float s = x0 + x1 + x2;
    for (int o = 32; o; o >>= 1) s += __shfl_xor(s, o);
    if (lane == 0) red[wid] = s;
    __syncthreads();
    float mean = (red[0] + red[1] + red[2] + red[3]) * (1.0f / 768.0f);

    float c0 = x0 - mean, c1 = x1 - mean, c2 = x2 - mean;
    float ss = c0 * c0 + c1 * c1 + c2 * c2;
    for (int o = 32; o; o >>= 1) ss += __shfl_xor(ss, o);
    __syncthreads();
    if (lane == 0) red[wid] = ss;
    __syncthreads();
    float var = (red[0] + red[1] + red[2] + red[3]) * (1.0f / 768.0f);
    float sd = var + EPSF;
    float scale = 1.0f / (sd * sd);

    h16* xr = xn + (size_t)row * H_;
    h16* cr = condb + (size_t)row * H_;
    xr[t] = (h16)(c0 * scale); xr[t + 256] = (h16)(c1 * scale); xr[t + 512] = (h16)(c2 * scale);
    cr[t] = (h16)x0;           cr[t + 256] = (h16)x1;           cr[t + 512] = (h16)x2;
}

// ============ kernel 2: cond GEMM -> gamma_c / beta_c (f16) ============
// C[p][o] = sum_h cond[p][h] * W[o][h] + bias[o];  tiles 64x64, BK=64
// grid (16, 24): by<12 -> gamma cols by*64 ; else beta cols (by-12)*64
__global__ __launch_bounds__(256) void k_cond_gemm(
    const h16* __restrict__ Ab, const h16* __restrict__ Wg, const h16* __restrict__ Wb,
    const float* __restrict__ gamma, const float* __restrict__ beta,
    h16* __restrict__ Gc, h16* __restrict__ Bc)
{
    __shared__ h16 Ash[64 * 72];
    __shared__ h16 Bsh[64 * 72];
    const int t = threadIdx.x;
    const int row0 = blockIdx.x * 64;
    const int by = blockIdx.y;
    const bool isg = (by < 12);
    const int nc0 = (isg ? by : by - 12) * 64;
    const h16* wsrc = isg ? Wg : Wb;

    const int r = t >> 2, q = t & 3;               // r in [0,64), 16 elems each at q*16
    const h16* ap = Ab + (size_t)(row0 + r) * H_ + q * 16;
    const h16* wp = wsrc + (size_t)(nc0 + r) * H_ + q * 16;
    h16* asto = &Ash[r * 72 + q * 16];
    h16* bsto = &Bsh[r * 72 + q * 16];

    const int lane = t & 63, wid = t >> 6;
    const int wm0 = (wid >> 1) * 32, wn0 = (wid & 1) * 32;
    const int l15 = lane & 15, quad = lane >> 4, q8 = quad * 8;

    f32x4 acc[2][2] = {};
    for (int kt = 0; kt < 12; ++kt) {
        const int k0 = kt * 64;
        uint4 a0 = *(const uint4*)(ap + k0); uint4 a1 = *(const uint4*)(ap + k0 + 8);
        uint4 w0 = *(const uint4*)(wp + k0); uint4 w1 = *(const uint4*)(wp + k0 + 8);
        *(uint4*)asto = a0; *(uint4*)(asto + 8) = a1;
        *(uint4*)bsto = w0; *(uint4*)(bsto + 8) = w1;
        __syncthreads();
#pragma unroll
        for (int ks = 0; ks < 64; ks += 32) {
            ffrag af[2], bf[2];
#pragma unroll
            for (int mi = 0; mi < 2; ++mi)
                af[mi] = *reinterpret_cast<const ffrag*>(&Ash[(wm0 + mi * 16 + l15) * 72 + ks + q8]);
#pragma unroll
            for (int ni = 0; ni < 2; ++ni)
                bf[ni] = *reinterpret_cast<const ffrag*>(&Bsh[(wn0 + ni * 16 + l15) * 72 + ks + q8]);
#pragma unroll
            for (int mi = 0; mi < 2; ++mi)
#pragma unroll
                for (int ni = 0; ni < 2; ++ni)
                    acc[mi][ni] = __builtin_amdgcn_mfma_f32_16x16x32_f16(af[mi], bf[ni], acc[mi][ni], 0, 0, 0);
        }
        __syncthreads();
    }

    const float* bias = isg ? gamma : beta;
    h16* outp = isg ? Gc : Bc;
#pragma unroll
    for (int mi = 0; mi < 2; ++mi)
#pragma unroll
        for (int ni = 0; ni < 2; ++ni) {
            int c = wn0 + ni * 16 + l15;
            float bv = bias[nc0 + c];
#pragma unroll
            for (int reg = 0; reg < 4; ++reg) {
                int rg = wm0 + mi * 16 + quad * 4 + reg;   // C/D: col=lane&15, row=quad*4+reg (m89)
                outp[(size_t)(row0 + rg) * H_ + nc0 + c] = (h16)(acc[mi][ni][reg] + bv);
            }
        }
}

// ============ kernel 2b: T[p][n] = bc[p] @ WcT[n] + biasc[n]  (f32 out) ============
// M=1024, N=384, K=768; 64x64 tiles, grid (16, 6)
__global__ __launch_bounds__(256) void k_tmat(
    const h16* __restrict__ Bcb, const h16* __restrict__ WcT,
    const float* __restrict__ biasc, float* __restrict__ T)
{
    __shared__ h16 Ash[64 * 72];
    __shared__ h16 Bsh[64 * 72];
    const int t = threadIdx.x;
    const int row0 = blockIdx.x * 64;
    const int nc0 = blockIdx.y * 64;

    const int r = t >> 2, q = t & 3;
    const h16* ap = Bcb + (size_t)(row0 + r) * H_ + q * 16;
    const h16* wp = WcT + (size_t)(nc0 + r) * H_ + q * 16;
    h16* asto = &Ash[r * 72 + q * 16];
    h16* bsto = &Bsh[r * 72 + q * 16];

    const int lane = t & 63, wid = t >> 6;
    const int wm0 = (wid >> 1) * 32, wn0 = (wid & 1) * 32;
    const int l15 = lane & 15, quad = lane >> 4, q8 = quad * 8;

    f32x4 acc[2][2] = {};
    for (int kt = 0; kt < 12; ++kt) {
        const int k0 = kt * 64;
        uint4 a0 = *(const uint4*)(ap + k0); uint4 a1 = *(const uint4*)(ap + k0 + 8);
        uint4 w0 = *(const uint4*)(wp + k0); uint4 w1 = *(const uint4*)(wp + k0 + 8);
        *(uint4*)asto = a0; *(uint4*)(asto + 8) = a1;
        *(uint4*)bsto = w0; *(uint4*)(bsto + 8) = w1;
        __syncthreads();
#pragma unroll
        for (int ks = 0; ks < 64; ks += 32) {
            ffrag af[2], bf[2];
#pragma unroll
            for (int mi = 0; mi < 2; ++mi)
                af[mi] = *reinterpret_cast<const ffrag*>(&Ash[(wm0 + mi * 16 + l15) * 72 + ks + q8]);
#pragma unroll
            for (int ni = 0; ni < 2; ++ni)
                bf[ni] = *reinterpret_cast<const ffrag*>(&Bsh[(wn0 + ni * 16 + l15) * 72 + ks + q8]);
#pragma unroll
            for (int mi = 0; mi < 2; ++mi)
#pragma unroll
                for (int ni = 0; ni < 2; ++ni)
                    acc[mi][ni] = __builtin_amdgcn_mfma_f32_16x16x32_f16(af[mi], bf[ni], acc[mi][ni], 0, 0, 0);
        }
        __syncthreads();
    }

#pragma unroll
    for (int mi = 0; mi < 2; ++mi)
#pragma unroll
        for (int ni = 0; ni < 2; ++ni) {
            int c = nc0 + wn0 + ni * 16 + l15;
            float bv = biasc[c];
#pragma unroll
            for (int reg = 0; reg < 4; ++reg) {
                int rg = wm0 + mi * 16 + quad * 4 + reg;
                T[(size_t)(row0 + rg) * 384 + c] = acc[mi][ni][reg] + bv;
            }
        }
}

// ============ kernel 3: barrier-free fused pair GEMM ============
// out[head, gp, m] = tanh( (xn[b,j] * gc[b,i]) @ W[:, cg]  +  T[b*128+i, cg] )
// A/B fragments gathered DIRECTLY from global (L2-resident), no LDS, no
// __syncthreads in the K-loop. Wave tile 64x96; block 128 rows x 192 cols.
// 1-deep register pipeline: next step's 14 b128 loads issued before MFMAs.
__global__ __launch_bounds__(256, 2) void k_pair_gemm(
    const h16* __restrict__ Xn, const h16* __restrict__ Gcb,
    const h16* __restrict__ WcT, const float* __restrict__ T,
    float* __restrict__ out)
{
    __shared__ int offx[128];   // xn row index (b*128 + j)
    __shared__ int offc[128];   // cond row index (b*128 + i)

    const int t = threadIdx.x;
    const int row0 = blockIdx.x * 128;
    const int nb = blockIdx.y;              // 0/1 -> cols [0,192) / [192,384)

    if (t < 128) {
        int gp = row0 + t;
        int b = gp / P_;
        int p = gp - b * P_;
        int i = (int)((257.0f - sqrtf(66049.0f - 8.0f * (float)p)) * 0.5f);
        if (i < 0) i = 0; if (i > 127) i = 127;
        while (i > 0 && (i * (257 - i)) / 2 > p) --i;
        while (((i + 1) * (256 - i)) / 2 <= p) ++i;
        int j = i + (p - (i * (257 - i)) / 2);
        offx[t] = b * 128 + j;
        offc[t] = b * 128 + i;
    }
    __syncthreads();

    const int lane = t & 63, wid = t >> 6;
    const int wm0 = (wid >> 1) * 64;        // wave row offset in [0,128)
    const int wn0 = (wid & 1) * 96;         // wave col offset in [0,192)
    const int l15 = lane & 15, quad = lane >> 4;

    // per-lane fragment base pointers (k advances by immediate offsets)
    const h16* xptr[4]; const h16* gptr[4];
#pragma unroll
    for (int mi = 0; mi < 4; ++mi) {
        int rl = wm0 + mi * 16 + l15;
        xptr[mi] = Xn  + (size_t)offx[rl] * H_ + quad * 8;
        gptr[mi] = Gcb + (size_t)offc[rl] * H_ + quad * 8;
    }
    const h16* bptr[6];
#pragma unroll
    for (int ni = 0; ni < 6; ++ni) {
        int cg = nb * 192 + wn0 + ni * 16 + l15;
        bptr[ni] = WcT + (size_t)cg * H_ + quad * 8;
    }

    f32x4 acc[4][6] = {};
    uint4 xv[4], gv[4], wv[6];
#pragma unroll
    for (int mi = 0; mi < 4; ++mi) { xv[mi] = *(const uint4*)xptr[mi]; gv[mi] = *(const uint4*)gptr[mi]; }
#pragma unroll
    for (int ni = 0; ni < 6; ++ni) wv[ni] = *(const uint4*)bptr[ni];

#pragma unroll
    for (int kt = 0; kt < 24; ++kt) {
        uint4 xn_[4], gn_[4], wn_[6];
        if (kt < 23) {
            const int ko = (kt + 1) * 32;
#pragma unroll
            for (int mi = 0; mi < 4; ++mi) {
                xn_[mi] = *(const uint4*)(xptr[mi] + ko);
                gn_[mi] = *(const uint4*)(gptr[mi] + ko);
            }
#pragma unroll
            for (int ni = 0; ni < 6; ++ni) wn_[ni] = *(const uint4*)(bptr[ni] + ko);
        }
        ffrag af[4], bf[6];
#pragma unroll
        for (int mi = 0; mi < 4; ++mi) {
            uint4 a;
            a.x = mul2(xv[mi].x, gv[mi].x); a.y = mul2(xv[mi].y, gv[mi].y);
            a.z = mul2(xv[mi].z, gv[mi].z); a.w = mul2(xv[mi].w, gv[mi].w);
            af[mi] = __builtin_bit_cast(ffrag, a);
        }
#pragma unroll
        for (int ni = 0; ni < 6; ++ni) bf[ni] = __builtin_bit_cast(ffrag, wv[ni]);
#pragma unroll
        for (int mi = 0; mi < 4; ++mi)
#pragma unroll
            for (int ni = 0; ni < 6; ++ni)
                acc[mi][ni] = __builtin_amdgcn_mfma_f32_16x16x32_f16(af[mi], bf[ni], acc[mi][ni], 0, 0, 0);
        if (kt < 23) {
#pragma unroll
            for (int mi = 0; mi < 4; ++mi) { xv[mi] = xn_[mi]; gv[mi] = gn_[mi]; }
#pragma unroll
            for (int ni = 0; ni < 6; ++ni) wv[ni] = wn_[ni];
        }
    }

    // epilogue: add T[b*128+i, cg], tanh, store
#pragma unroll
    for (int mi = 0; mi < 4; ++mi) {
        int trow[4];
#pragma unroll
        for (int reg = 0; reg < 4; ++reg) trow[reg] = offc[wm0 + mi * 16 + quad * 4 + reg];
#pragma unroll
        for (int ni = 0; ni < 6; ++ni) {
            int cg = nb * 192 + wn0 + ni * 16 + l15;
            int head = cg >> 7, m = cg & 127;
#pragma unroll
            for (int reg = 0; reg < 4; ++reg) {
                int rg = wm0 + mi * 16 + quad * 4 + reg;
                float tv = T[(size_t)trow[reg] * 384 + cg];
                out[((size_t)head * BP_ + row0 + rg) * M_ + m] = fast_tanh(acc[mi][ni][reg] + tv);
            }
        }
    }
}

extern "C" void kernel_launch(void* const* d_in, const int* in_sizes, int n_in,
                              void* d_out, int out_size, void* d_ws, size_t ws_size,
                              hipStream_t stream)
{
    const float* seq     = (const float*)d_in[0];
    const float* gamma   = (const float*)d_in[1];
    const float* beta    = (const float*)d_in[2];
    const float* w_beta  = (const float*)d_in[3];
    const float* w_gamma = (const float*)d_in[4];
    const float* w_ent   = (const float*)d_in[5];
    const float* b_ent   = (const float*)d_in[6];
    const float* w_head  = (const float*)d_in[7];
    const float* b_head  = (const float*)d_in[8];
    const float* w_tail  = (const float*)d_in[9];
    const float* b_tail  = (const float*)d_in[10];
    float* out = (float*)d_out;

    // workspace layout (all 16B-aligned)
    char* ws = (char*)d_ws;
    h16* xn    = (h16*)ws; ws += (size_t)1024 * 768 * 2;  // normalized rows, f16
    h16* condb = (h16*)ws; ws += (size_t)1024 * 768 * 2;  // seq as f16
    h16* wgb   = (h16*)ws; ws += (size_t)768 * 768 * 2;   // w_gamma f16 [o][h]
    h16* wbb   = (h16*)ws; ws += (size_t)768 * 768 * 2;   // w_beta  f16 [o][h]
    h16* wct   = (h16*)ws; ws += (size_t)384 * 768 * 2;   // [n][h] combined ent|head|tail
    h16* gc    = (h16*)ws; ws += (size_t)1024 * 768 * 2;  // gamma_c f16
    h16* bc    = (h16*)ws; ws += (size_t)1024 * 768 * 2;  // beta_c  f16
    float* biasc = (float*)ws; ws += 384 * 4;             // [ent|head|tail] bias
    float* T     = (float*)ws; ws += (size_t)1024 * 384 * 4;  // bc @ W + bias (f32)

    hipLaunchKernelGGL(k_convert, dim3(5763), dim3(256), 0, stream,
                       w_gamma, w_beta, w_ent, w_head, w_tail, b_ent, b_head, b_tail,
                       wgb, wbb, wct, biasc);
    hipLaunchKernelGGL(k_norm, dim3(1024), dim3(256), 0, stream, seq, xn, condb);
    hipLaunchKernelGGL(k_cond_gemm, dim3(16, 24), dim3(256), 0, stream,
                       condb, wgb, wbb, gamma, beta, gc, bc);
    hipLaunchKernelGGL(k_tmat, dim3(16, 6), dim3(256), 0, stream,
                       bc, wct, biasc, T);
    hipLaunchKernelGGL(k_pair_gemm, dim3(516, 2), dim3(256), 0, stream,
                       xn, gc, wct, T, out);
}

// Round 4
// 235.903 us; speedup vs baseline: 1.3298x; 1.3298x over previous
//
#include <hip/hip_runtime.h>
#include <hip/hip_bf16.h>
#include <hip/hip_fp16.h>
#include <math.h>

// Problem constants (B,S,H,M) = (8,128,768,128)
#define B_   8
#define S_   128
#define H_   768
#define M_   128
#define P_   8256      // S*(S+1)/2 pairs per batch
#define BP_  66048     // B_ * P_
#define EPSF 1e-12f

typedef unsigned short u16;
typedef unsigned int   u32;
typedef _Float16 h16;
typedef _Float16 ffrag __attribute__((ext_vector_type(8)));   // 8 f16 = 4 VGPR
typedef float    f32x4 __attribute__((ext_vector_type(4)));

__device__ __forceinline__ u32 mul2(u32 x, u32 g) {
    __half2 r = __hmul2(__builtin_bit_cast(__half2, x), __builtin_bit_cast(__half2, g));
    return __builtin_bit_cast(u32, r);
}
__device__ __forceinline__ float fast_tanh(float v) {
    float e = __expf(-2.0f * fabsf(v));
    float t = (1.0f - e) / (1.0f + e);
    return copysignf(t, v);
}
// async global->LDS 16B per lane; lds dst must be the wave-uniform base
__device__ __forceinline__ void gl_lds16(const h16* g, h16* l) {
    __builtin_amdgcn_global_load_lds(
        (const __attribute__((address_space(1))) u32*)g,
        (__attribute__((address_space(3))) u32*)l, 16, 0, 0);
}

// ============ kernel 0: convert weights to f16; build WcT[n][h]; biasc ============
__global__ void k_convert(const float* __restrict__ wg, const float* __restrict__ wb,
                          const float* __restrict__ we, const float* __restrict__ wh,
                          const float* __restrict__ wt,
                          const float* __restrict__ be, const float* __restrict__ bh,
                          const float* __restrict__ bt,
                          h16* __restrict__ wgb, h16* __restrict__ wbb,
                          h16* __restrict__ wct, float* __restrict__ biasc)
{
    int idx = blockIdx.x * 256 + threadIdx.x;
    if (idx < 589824) {
        wgb[idx] = (h16)wg[idx];
    } else if (idx < 1179648) {
        int i = idx - 589824;
        wbb[i] = (h16)wb[i];
    } else if (idx < 1474560) {
        int i = idx - 1179648;              // [0, 294912) : n in [0,384), h in [0,768)
        int n = i / 768, h = i - n * 768;
        const float* w = (n < 128) ? we : (n < 256 ? wh : wt);
        wct[i] = (h16)w[h * 128 + (n & 127)];
    } else if (idx < 1474944) {
        int n = idx - 1474560;              // [0,384)
        biasc[n] = (n < 128) ? be[n] : (n < 256 ? bh[n - 128] : bt[n - 256]);
    }
}

// ============ kernel 1: per-row normalize + seq->f16 ============
// xn[row] = (x - mean) / (var + eps)^2   (reference squares, no sqrt!)
__global__ void k_norm(const float* __restrict__ seq, h16* __restrict__ xn, h16* __restrict__ condb)
{
    __shared__ float red[4];
    const int row = blockIdx.x;
    const int t = threadIdx.x;
    const int lane = t & 63, wid = t >> 6;
    const float* x = seq + (size_t)row * H_;
    float x0 = x[t], x1 = x[t + 256], x2 = x[t + 512];

    float s = x0 + x1 + x2;
    for (int o = 32; o; o >>= 1) s += __shfl_xor(s, o);
    if (lane == 0) red[wid] = s;
    __syncthreads();
    float mean = (red[0] + red[1] + red[2] + red[3]) * (1.0f / 768.0f);

    float c0 = x0 - mean, c1 = x1 - mean, c2 = x2 - mean;
    float ss = c0 * c0 + c1 * c1 + c2 * c2;
    for (int o = 32; o; o >>= 1) ss += __shfl_xor(ss, o);
    __syncthreads();
    if (lane == 0) red[wid] = ss;
    __syncthreads();
    float var = (red[0] + red[1] + red[2] + red[3]) * (1.0f / 768.0f);
    float sd = var + EPSF;
    float scale = 1.0f / (sd * sd);

    h16* xr = xn + (size_t)row * H_;
    h16* cr = condb + (size_t)row * H_;
    xr[t] = (h16)(c0 * scale); xr[t + 256] = (h16)(c1 * scale); xr[t + 512] = (h16)(c2 * scale);
    cr[t] = (h16)x0;           cr[t + 256] = (h16)x1;           cr[t + 512] = (h16)x2;
}

// ============ kernel 2: cond GEMM -> gamma_c / beta_c (f16) ============
__global__ __launch_bounds__(256) void k_cond_gemm(
    const h16* __restrict__ Ab, const h16* __restrict__ Wg, const h16* __restrict__ Wb,
    const float* __restrict__ gamma, const float* __restrict__ beta,
    h16* __restrict__ Gc, h16* __restrict__ Bc)
{
    __shared__ h16 Ash[64 * 72];
    __shared__ h16 Bsh[64 * 72];
    const int t = threadIdx.x;
    const int row0 = blockIdx.x * 64;
    const int by = blockIdx.y;
    const bool isg = (by < 12);
    const int nc0 = (isg ? by : by - 12) * 64;
    const h16* wsrc = isg ? Wg : Wb;

    const int r = t >> 2, q = t & 3;
    const h16* ap = Ab + (size_t)(row0 + r) * H_ + q * 16;
    const h16* wp = wsrc + (size_t)(nc0 + r) * H_ + q * 16;
    h16* asto = &Ash[r * 72 + q * 16];
    h16* bsto = &Bsh[r * 72 + q * 16];

    const int lane = t & 63, wid = t >> 6;
    const int wm0 = (wid >> 1) * 32, wn0 = (wid & 1) * 32;
    const int l15 = lane & 15, quad = lane >> 4, q8 = quad * 8;

    f32x4 acc[2][2] = {};
    for (int kt = 0; kt < 12; ++kt) {
        const int k0 = kt * 64;
        uint4 a0 = *(const uint4*)(ap + k0); uint4 a1 = *(const uint4*)(ap + k0 + 8);
        uint4 w0 = *(const uint4*)(wp + k0); uint4 w1 = *(const uint4*)(wp + k0 + 8);
        *(uint4*)asto = a0; *(uint4*)(asto + 8) = a1;
        *(uint4*)bsto = w0; *(uint4*)(bsto + 8) = w1;
        __syncthreads();
#pragma unroll
        for (int ks = 0; ks < 64; ks += 32) {
            ffrag af[2], bf[2];
#pragma unroll
            for (int mi = 0; mi < 2; ++mi)
                af[mi] = *reinterpret_cast<const ffrag*>(&Ash[(wm0 + mi * 16 + l15) * 72 + ks + q8]);
#pragma unroll
            for (int ni = 0; ni < 2; ++ni)
                bf[ni] = *reinterpret_cast<const ffrag*>(&Bsh[(wn0 + ni * 16 + l15) * 72 + ks + q8]);
#pragma unroll
            for (int mi = 0; mi < 2; ++mi)
#pragma unroll
                for (int ni = 0; ni < 2; ++ni)
                    acc[mi][ni] = __builtin_amdgcn_mfma_f32_16x16x32_f16(af[mi], bf[ni], acc[mi][ni], 0, 0, 0);
        }
        __syncthreads();
    }

    const float* bias = isg ? gamma : beta;
    h16* outp = isg ? Gc : Bc;
#pragma unroll
    for (int mi = 0; mi < 2; ++mi)
#pragma unroll
        for (int ni = 0; ni < 2; ++ni) {
            int c = wn0 + ni * 16 + l15;
            float bv = bias[nc0 + c];
#pragma unroll
            for (int reg = 0; reg < 4; ++reg) {
                int rg = wm0 + mi * 16 + quad * 4 + reg;   // C/D: col=lane&15, row=quad*4+reg (m89)
                outp[(size_t)(row0 + rg) * H_ + nc0 + c] = (h16)(acc[mi][ni][reg] + bv);
            }
        }
}

// ============ kernel 2b: T[p][n] = bc[p] @ WcT[n] + biasc[n]  (f32 out) ============
__global__ __launch_bounds__(256) void k_tmat(
    const h16* __restrict__ Bcb, const h16* __restrict__ WcT,
    const float* __restrict__ biasc, float* __restrict__ T)
{
    __shared__ h16 Ash[64 * 72];
    __shared__ h16 Bsh[64 * 72];
    const int t = threadIdx.x;
    const int row0 = blockIdx.x * 64;
    const int nc0 = blockIdx.y * 64;

    const int r = t >> 2, q = t & 3;
    const h16* ap = Bcb + (size_t)(row0 + r) * H_ + q * 16;
    const h16* wp = WcT + (size_t)(nc0 + r) * H_ + q * 16;
    h16* asto = &Ash[r * 72 + q * 16];
    h16* bsto = &Bsh[r * 72 + q * 16];

    const int lane = t & 63, wid = t >> 6;
    const int wm0 = (wid >> 1) * 32, wn0 = (wid & 1) * 32;
    const int l15 = lane & 15, quad = lane >> 4, q8 = quad * 8;

    f32x4 acc[2][2] = {};
    for (int kt = 0; kt < 12; ++kt) {
        const int k0 = kt * 64;
        uint4 a0 = *(const uint4*)(ap + k0); uint4 a1 = *(const uint4*)(ap + k0 + 8);
        uint4 w0 = *(const uint4*)(wp + k0); uint4 w1 = *(const uint4*)(wp + k0 + 8);
        *(uint4*)asto = a0; *(uint4*)(asto + 8) = a1;
        *(uint4*)bsto = w0; *(uint4*)(bsto + 8) = w1;
        __syncthreads();
#pragma unroll
        for (int ks = 0; ks < 64; ks += 32) {
            ffrag af[2], bf[2];
#pragma unroll
            for (int mi = 0; mi < 2; ++mi)
                af[mi] = *reinterpret_cast<const ffrag*>(&Ash[(wm0 + mi * 16 + l15) * 72 + ks + q8]);
#pragma unroll
            for (int ni = 0; ni < 2; ++ni)
                bf[ni] = *reinterpret_cast<const ffrag*>(&Bsh[(wn0 + ni * 16 + l15) * 72 + ks + q8]);
#pragma unroll
            for (int mi = 0; mi < 2; ++mi)
#pragma unroll
                for (int ni = 0; ni < 2; ++ni)
                    acc[mi][ni] = __builtin_amdgcn_mfma_f32_16x16x32_f16(af[mi], bf[ni], acc[mi][ni], 0, 0, 0);
        }
        __syncthreads();
    }

#pragma unroll
    for (int mi = 0; mi < 2; ++mi)
#pragma unroll
        for (int ni = 0; ni < 2; ++ni) {
            int c = nc0 + wn0 + ni * 16 + l15;
            float bv = biasc[c];
#pragma unroll
            for (int reg = 0; reg < 4; ++reg) {
                int rg = wm0 + mi * 16 + quad * 4 + reg;
                T[(size_t)(row0 + rg) * 384 + c] = acc[mi][ni][reg] + bv;
            }
        }
}

// ============ kernel 3: m97-style fused pair GEMM ============
// out[head, gp, m] = tanh( (xn[b,j] * gc[b,i]) @ W[:, cg]  +  T[b*128+i, cg] )
// Block 128 rows x 192 cols, BK=32, 24 iters, double-buffered LDS:
//   B staged via global_load_lds width=16 (async DMA, unpadded [192][32])
//   A staged via coalesced b128 loads + v_pk_mul_f16 fuse + ds_write_b128
// One barrier per K-iter.
__global__ __launch_bounds__(256) void k_pair_gemm(
    const h16* __restrict__ Xn, const h16* __restrict__ Gcb,
    const h16* __restrict__ WcT, const float* __restrict__ T,
    float* __restrict__ out)
{
    __shared__ h16 Ash[2][128 * 32];   // 8 KB each
    __shared__ h16 Bsh[2][192 * 32];   // 12 KB each
    __shared__ int offx[128];          // xn row index (b*128 + j)
    __shared__ int offc[128];          // cond row index (b*128 + i)

    const int t = threadIdx.x;
    const int row0 = blockIdx.x * 128;
    const int nb = blockIdx.y;              // 0/1 -> cols [0,192) / [192,384)

    if (t < 128) {
        int gp = row0 + t;
        int b = gp / P_;
        int p = gp - b * P_;
        int i = (int)((257.0f - sqrtf(66049.0f - 8.0f * (float)p)) * 0.5f);
        if (i < 0) i = 0; if (i > 127) i = 127;
        while (i > 0 && (i * (257 - i)) / 2 > p) --i;
        while (((i + 1) * (256 - i)) / 2 <= p) ++i;
        int j = i + (p - (i * (257 - i)) / 2);
        offx[t] = b * 128 + j;
        offc[t] = b * 128 + i;
    }
    __syncthreads();

    // ---- A staging addresses: thread covers row r=t>>1, 16 h16 at (t&1)*16 ----
    const int r = t >> 1, half = t & 1;
    const h16* xp = Xn  + (size_t)offx[r] * H_ + half * 16;
    const h16* gp_ = Gcb + (size_t)offc[r] * H_ + half * 16;
    const int aoff = r * 32 + half * 16;

    // ---- B DMA: 3 chunks; lane-linear L = c*256+t -> row L>>2, kq = L&3 ----
    const h16* wbase = WcT + (size_t)nb * 192 * H_;
    const int wud = (t & ~63);              // wave-uniform within chunk

    const int lane = t & 63, wid = t >> 6;
    const int wm0 = (wid >> 1) * 64, wn0 = (wid & 1) * 96;
    const int l15 = lane & 15, quad = lane >> 4, q8 = quad * 8;

    // ---------- prologue: stage kt=0 into buffer 0 ----------
#pragma unroll
    for (int c = 0; c < 3; ++c) {
        int L = c * 256 + t;
        gl_lds16(wbase + (size_t)(L >> 2) * H_ + (L & 3) * 8, &Bsh[0][(c * 256 + wud) * 8]);
    }
    {
        uint4 xv0 = *(const uint4*)xp;        uint4 xv1 = *(const uint4*)(xp + 8);
        uint4 gv0 = *(const uint4*)gp_;       uint4 gv1 = *(const uint4*)(gp_ + 8);
        uint4 a0, a1;
        a0.x = mul2(xv0.x, gv0.x); a0.y = mul2(xv0.y, gv0.y);
        a0.z = mul2(xv0.z, gv0.z); a0.w = mul2(xv0.w, gv0.w);
        a1.x = mul2(xv1.x, gv1.x); a1.y = mul2(xv1.y, gv1.y);
        a1.z = mul2(xv1.z, gv1.z); a1.w = mul2(xv1.w, gv1.w);
        *(uint4*)&Ash[0][aoff] = a0; *(uint4*)&Ash[0][aoff + 8] = a1;
    }
    __syncthreads();   // (compiler inserts vmcnt(0)+lgkmcnt(0): buffer 0 ready)

    f32x4 acc[4][6] = {};
    for (int kt = 0; kt < 24; ++kt) {
        const int buf = kt & 1, nbuf = buf ^ 1;
        uint4 xv0, xv1, gv0, gv1;
        if (kt < 23) {
            const int k0 = (kt + 1) * 32;
            // issue next B DMA (into nbuf — WAR-safe: barrier above ensured all
            // waves finished reading nbuf in iter kt-1)
#pragma unroll
            for (int c = 0; c < 3; ++c) {
                int L = c * 256 + t;
                gl_lds16(wbase + (size_t)(L >> 2) * H_ + k0 + (L & 3) * 8,
                         &Bsh[nbuf][(c * 256 + wud) * 8]);
            }
            // issue next A loads (VGPR), consumed after the MFMAs below
            xv0 = *(const uint4*)(xp + k0);  xv1 = *(const uint4*)(xp + k0 + 8);
            gv0 = *(const uint4*)(gp_ + k0); gv1 = *(const uint4*)(gp_ + k0 + 8);
        }

        ffrag af[4], bf[6];
#pragma unroll
        for (int mi = 0; mi < 4; ++mi)
            af[mi] = *reinterpret_cast<const ffrag*>(&Ash[buf][(wm0 + mi * 16 + l15) * 32 + q8]);
#pragma unroll
        for (int ni = 0; ni < 6; ++ni)
            bf[ni] = *reinterpret_cast<const ffrag*>(&Bsh[buf][(wn0 + ni * 16 + l15) * 32 + q8]);
#pragma unroll
        for (int mi = 0; mi < 4; ++mi)
#pragma unroll
            for (int ni = 0; ni < 6; ++ni)
                acc[mi][ni] = __builtin_amdgcn_mfma_f32_16x16x32_f16(af[mi], bf[ni], acc[mi][ni], 0, 0, 0);

        if (kt < 23) {
            uint4 a0, a1;
            a0.x = mul2(xv0.x, gv0.x); a0.y = mul2(xv0.y, gv0.y);
            a0.z = mul2(xv0.z, gv0.z); a0.w = mul2(xv0.w, gv0.w);
            a1.x = mul2(xv1.x, gv1.x); a1.y = mul2(xv1.y, gv1.y);
            a1.z = mul2(xv1.z, gv1.z); a1.w = mul2(xv1.w, gv1.w);
            *(uint4*)&Ash[nbuf][aoff] = a0; *(uint4*)&Ash[nbuf][aoff + 8] = a1;
        }
        __syncthreads();
    }

    // epilogue: add T[b*128+i, cg], tanh, store
#pragma unroll
    for (int mi = 0; mi < 4; ++mi) {
        int trow[4];
#pragma unroll
        for (int reg = 0; reg < 4; ++reg) trow[reg] = offc[wm0 + mi * 16 + quad * 4 + reg];
#pragma unroll
        for (int ni = 0; ni < 6; ++ni) {
            int cg = nb * 192 + wn0 + ni * 16 + l15;
            int head = cg >> 7, m = cg & 127;
#pragma unroll
            for (int reg = 0; reg < 4; ++reg) {
                int rg = wm0 + mi * 16 + quad * 4 + reg;
                float tv = T[(size_t)trow[reg] * 384 + cg];
                out[((size_t)head * BP_ + row0 + rg) * M_ + m] = fast_tanh(acc[mi][ni][reg] + tv);
            }
        }
    }
}

extern "C" void kernel_launch(void* const* d_in, const int* in_sizes, int n_in,
                              void* d_out, int out_size, void* d_ws, size_t ws_size,
                              hipStream_t stream)
{
    const float* seq     = (const float*)d_in[0];
    const float* gamma   = (const float*)d_in[1];
    const float* beta    = (const float*)d_in[2];
    const float* w_beta  = (const float*)d_in[3];
    const float* w_gamma = (const float*)d_in[4];
    const float* w_ent   = (const float*)d_in[5];
    const float* b_ent   = (const float*)d_in[6];
    const float* w_head  = (const float*)d_in[7];
    const float* b_head  = (const float*)d_in[8];
    const float* w_tail  = (const float*)d_in[9];
    const float* b_tail  = (const float*)d_in[10];
    float* out = (float*)d_out;

    // workspace layout (all 16B-aligned)
    char* ws = (char*)d_ws;
    h16* xn    = (h16*)ws; ws += (size_t)1024 * 768 * 2;  // normalized rows, f16
    h16* condb = (h16*)ws; ws += (size_t)1024 * 768 * 2;  // seq as f16
    h16* wgb   = (h16*)ws; ws += (size_t)768 * 768 * 2;   // w_gamma f16 [o][h]
    h16* wbb   = (h16*)ws; ws += (size_t)768 * 768 * 2;   // w_beta  f16 [o][h]
    h16* wct   = (h16*)ws; ws += (size_t)384 * 768 * 2;   // [n][h] combined ent|head|tail
    h16* gc    = (h16*)ws; ws += (size_t)1024 * 768 * 2;  // gamma_c f16
    h16* bc    = (h16*)ws; ws += (size_t)1024 * 768 * 2;  // beta_c  f16
    float* biasc = (float*)ws; ws += 384 * 4;             // [ent|head|tail] bias
    float* T     = (float*)ws; ws += (size_t)1024 * 384 * 4;  // bc @ W + bias (f32)

    hipLaunchKernelGGL(k_convert, dim3(5763), dim3(256), 0, stream,
                       w_gamma, w_beta, w_ent, w_head, w_tail, b_ent, b_head, b_tail,
                       wgb, wbb, wct, biasc);
    hipLaunchKernelGGL(k_norm, dim3(1024), dim3(256), 0, stream, seq, xn, condb);
    hipLaunchKernelGGL(k_cond_gemm, dim3(16, 24), dim3(256), 0, stream,
                       condb, wgb, wbb, gamma, beta, gc, bc);
    hipLaunchKernelGGL(k_tmat, dim3(16, 6), dim3(256), 0, stream,
                       bc, wct, biasc, T);
    hipLaunchKernelGGL(k_pair_gemm, dim3(516, 2), dim3(256), 0, stream,
                       xn, gc, wct, T, out);
}

// Round 5
// 235.058 us; speedup vs baseline: 1.3346x; 1.0036x over previous
//
#include <hip/hip_runtime.h>
#include <hip/hip_bf16.h>
#include <hip/hip_fp16.h>
#include <math.h>

// Problem constants (B,S,H,M) = (8,128,768,128)
#define B_   8
#define S_   128
#define H_   768
#define M_   128
#define P_   8256      // S*(S+1)/2 pairs per batch
#define BP_  66048     // B_ * P_
#define EPSF 1e-12f

typedef unsigned short u16;
typedef unsigned int   u32;
typedef _Float16 h16;
typedef _Float16 ffrag __attribute__((ext_vector_type(8)));   // 8 f16 = 4 VGPR
typedef float    f32x4 __attribute__((ext_vector_type(4)));

// packed f16 fma: one v_pk_fma_f16 for two lanes
__device__ __forceinline__ u32 fuse2(u32 x, u32 g, u32 b) {
    __half2 r = __hfma2(__builtin_bit_cast(__half2, x),
                        __builtin_bit_cast(__half2, g),
                        __builtin_bit_cast(__half2, b));
    return __builtin_bit_cast(u32, r);
}
// tanh(x) = 1 - 2/(e^{2x}+1): exp + rcp + fma, branch/copysign-free,
// correct at +-inf (rcp(inf)=0 -> 1; exp(-inf)=0 -> -1)
__device__ __forceinline__ float fast_tanh(float v) {
    float t = __expf(v + v);
    float r = __builtin_amdgcn_rcpf(t + 1.0f);
    return fmaf(-2.0f, r, 1.0f);
}
// async global->LDS 16B per lane; lds dst must be the wave-uniform base
__device__ __forceinline__ void gl_lds16(const h16* g, h16* l) {
    __builtin_amdgcn_global_load_lds(
        (const __attribute__((address_space(1))) u32*)g,
        (__attribute__((address_space(3))) u32*)l, 16, 0, 0);
}

// ============ kernel A: weight convert + per-row normalize (merged) ============
// blocks [0,5763): convert fp32 weights -> f16 (wgb, wbb, wct[n][h]), biasc
// blocks [5763, 5763+1024): row normalize; xn = (x-mean)/(var+eps)^2 (ref squares, no sqrt)
__global__ void k_prep(const float* __restrict__ seq,
                       const float* __restrict__ wg, const float* __restrict__ wb,
                       const float* __restrict__ we, const float* __restrict__ wh,
                       const float* __restrict__ wt,
                       const float* __restrict__ be, const float* __restrict__ bh,
                       const float* __restrict__ bt,
                       h16* __restrict__ wgb, h16* __restrict__ wbb,
                       h16* __restrict__ wct, float* __restrict__ biasc,
                       h16* __restrict__ xn, h16* __restrict__ condb)
{
    __shared__ float red[4];
    const int bx = blockIdx.x;
    const int t = threadIdx.x;

    if (bx < 5763) {   // ---- convert ----
        int idx = bx * 256 + t;
        if (idx < 589824) {
            wgb[idx] = (h16)wg[idx];
        } else if (idx < 1179648) {
            int i = idx - 589824;
            wbb[i] = (h16)wb[i];
        } else if (idx < 1474560) {
            int i = idx - 1179648;              // n in [0,384), h in [0,768)
            int n = i / 768, h = i - n * 768;
            const float* w = (n < 128) ? we : (n < 256 ? wh : wt);
            wct[i] = (h16)w[h * 128 + (n & 127)];
        } else if (idx < 1474944) {
            int n = idx - 1474560;
            biasc[n] = (n < 128) ? be[n] : (n < 256 ? bh[n - 128] : bt[n - 256]);
        }
        return;
    }
    // ---- normalize ----
    const int row = bx - 5763;
    const int lane = t & 63, wid = t >> 6;
    const float* x = seq + (size_t)row * H_;
    float x0 = x[t], x1 = x[t + 256], x2 = x[t + 512];

    float s = x0 + x1 + x2;
    for (int o = 32; o; o >>= 1) s += __shfl_xor(s, o);
    if (lane == 0) red[wid] = s;
    __syncthreads();
    float mean = (red[0] + red[1] + red[2] + red[3]) * (1.0f / 768.0f);

    float c0 = x0 - mean, c1 = x1 - mean, c2 = x2 - mean;
    float ss = c0 * c0 + c1 * c1 + c2 * c2;
    for (int o = 32; o; o >>= 1) ss += __shfl_xor(ss, o);
    __syncthreads();
    if (lane == 0) red[wid] = ss;
    __syncthreads();
    float var = (red[0] + red[1] + red[2] + red[3]) * (1.0f / 768.0f);
    float sd = var + EPSF;
    float scale = 1.0f / (sd * sd);

    h16* xr = xn + (size_t)row * H_;
    h16* cr = condb + (size_t)row * H_;
    xr[t] = (h16)(c0 * scale); xr[t + 256] = (h16)(c1 * scale); xr[t + 512] = (h16)(c2 * scale);
    cr[t] = (h16)x0;           cr[t + 256] = (h16)x1;           cr[t + 512] = (h16)x2;
}

// ============ kernel B: cond GEMM -> gamma_c / beta_c (f16) ============
// C[p][o] = sum_h cond[p][h] * W[o][h] + bias[o];  tiles 64x64, BK=64
// grid (16, 24): by<12 -> gamma cols by*64 ; else beta cols (by-12)*64
// LDS stride 72 h16 = 144 B: addr%128 takes 8 values over 16 rows -> conflict-free
__global__ __launch_bounds__(256) void k_cond_gemm(
    const h16* __restrict__ Ab, const h16* __restrict__ Wg, const h16* __restrict__ Wb,
    const float* __restrict__ gamma, const float* __restrict__ beta,
    h16* __restrict__ Gc, h16* __restrict__ Bc)
{
    __shared__ h16 Ash[64 * 72];
    __shared__ h16 Bsh[64 * 72];
    const int t = threadIdx.x;
    const int row0 = blockIdx.x * 64;
    const int by = blockIdx.y;
    const bool isg = (by < 12);
    const int nc0 = (isg ? by : by - 12) * 64;
    const h16* wsrc = isg ? Wg : Wb;

    const int r = t >> 2, q = t & 3;
    const h16* ap = Ab + (size_t)(row0 + r) * H_ + q * 16;
    const h16* wp = wsrc + (size_t)(nc0 + r) * H_ + q * 16;
    h16* asto = &Ash[r * 72 + q * 16];
    h16* bsto = &Bsh[r * 72 + q * 16];

    const int lane = t & 63, wid = t >> 6;
    const int wm0 = (wid >> 1) * 32, wn0 = (wid & 1) * 32;
    const int l15 = lane & 15, quad = lane >> 4, q8 = quad * 8;

    f32x4 acc[2][2] = {};
    for (int kt = 0; kt < 12; ++kt) {
        const int k0 = kt * 64;
        uint4 a0 = *(const uint4*)(ap + k0); uint4 a1 = *(const uint4*)(ap + k0 + 8);
        uint4 w0 = *(const uint4*)(wp + k0); uint4 w1 = *(const uint4*)(wp + k0 + 8);
        *(uint4*)asto = a0; *(uint4*)(asto + 8) = a1;
        *(uint4*)bsto = w0; *(uint4*)(bsto + 8) = w1;
        __syncthreads();
#pragma unroll
        for (int ks = 0; ks < 64; ks += 32) {
            ffrag af[2], bf[2];
#pragma unroll
            for (int mi = 0; mi < 2; ++mi)
                af[mi] = *reinterpret_cast<const ffrag*>(&Ash[(wm0 + mi * 16 + l15) * 72 + ks + q8]);
#pragma unroll
            for (int ni = 0; ni < 2; ++ni)
                bf[ni] = *reinterpret_cast<const ffrag*>(&Bsh[(wn0 + ni * 16 + l15) * 72 + ks + q8]);
#pragma unroll
            for (int mi = 0; mi < 2; ++mi)
#pragma unroll
                for (int ni = 0; ni < 2; ++ni)
                    acc[mi][ni] = __builtin_amdgcn_mfma_f32_16x16x32_f16(af[mi], bf[ni], acc[mi][ni], 0, 0, 0);
        }
        __syncthreads();
    }

    const float* bias = isg ? gamma : beta;
    h16* outp = isg ? Gc : Bc;
#pragma unroll
    for (int mi = 0; mi < 2; ++mi)
#pragma unroll
        for (int ni = 0; ni < 2; ++ni) {
            int c = wn0 + ni * 16 + l15;
            float bv = bias[nc0 + c];
#pragma unroll
            for (int reg = 0; reg < 4; ++reg) {
                int rg = wm0 + mi * 16 + quad * 4 + reg;   // C/D: col=lane&15, row=quad*4+reg (m89)
                outp[(size_t)(row0 + rg) * H_ + nc0 + c] = (h16)(acc[mi][ni][reg] + bv);
            }
        }
}

// ============ kernel C: fused pair GEMM ============
// out[head, gp, m] = tanh( (xn[b,j]*gc[b,i] + bc[b,i]) @ W[:, cg] + biasc[cg] )
// Block 128 rows x 192 cols, BK=32, 24 iters, double-buffered.
// LDS is CHUNK-MAJOR: slot(chunk,row) at (chunk*ROWS+row)*8 h16 — every
// fragment ds_read_b128 is 16 lanes x contiguous 16B = 2 lanes/bank (free),
// and B-DMA (wave-uniform base + lane*16) maps to lane-linear slots.
// Pipeline: DMA(B,kt+1) + A-loads(kt+1) at iter start; fuse+ds_write after
// MFMAs; barrier drains nothing recently issued.
__global__ __launch_bounds__(256, 2) void k_pair_gemm(
    const h16* __restrict__ Xn, const h16* __restrict__ Gcb, const h16* __restrict__ Bcb,
    const h16* __restrict__ WcT, const float* __restrict__ biasc,
    float* __restrict__ out)
{
    __shared__ h16 Ash[2][4 * 128 * 8];   // 8 KB per buf
    __shared__ h16 Bsh[2][4 * 192 * 8];   // 12 KB per buf
    __shared__ int offx[128];             // xn row index (b*128 + j)
    __shared__ int offc[128];             // cond row index (b*128 + i)

    const int t = threadIdx.x;
    const int row0 = blockIdx.x * 128;
    const int nb = blockIdx.y;            // 0/1 -> cols [0,192) / [192,384)

    if (t < 128) {
        int gp = row0 + t;
        int b = gp / P_;
        int p = gp - b * P_;
        int i = (int)((257.0f - sqrtf(66049.0f - 8.0f * (float)p)) * 0.5f);
        if (i < 0) i = 0; if (i > 127) i = 127;
        while (i > 0 && (i * (257 - i)) / 2 > p) --i;
        while (((i + 1) * (256 - i)) / 2 <= p) ++i;
        int j = i + (p - (i * (257 - i)) / 2);
        offx[t] = b * 128 + j;
        offc[t] = b * 128 + i;
    }
    __syncthreads();

    // A staging: thread covers row r=t>>1, k in [16h,16h+16) = chunks 2h,2h+1
    const int r = t >> 1, half = t & 1;
    const h16* xp  = Xn  + (size_t)offx[r] * H_ + half * 16;
    const h16* gp_ = Gcb + (size_t)offc[r] * H_ + half * 16;
    const h16* bp_ = Bcb + (size_t)offc[r] * H_ + half * 16;
    const int aw0 = ((2 * half) * 128 + r) * 8;
    const int aw1 = ((2 * half + 1) * 128 + r) * 8;

    // B DMA: slot L = c*256+t in [0,768): chunk = L/192, n = L%192
    const h16* wbase = WcT + (size_t)nb * 192 * H_;
    const int wud = t & ~63;
    const h16* dsrc[3];
#pragma unroll
    for (int c = 0; c < 3; ++c) {
        int L = c * 256 + t;
        int ch = L / 192, n = L - ch * 192;
        dsrc[c] = wbase + (size_t)n * H_ + ch * 8;
    }

    const int lane = t & 63, wid = t >> 6;
    const int wm0 = (wid >> 1) * 64, wn0 = (wid & 1) * 96;
    const int l15 = lane & 15, quad = lane >> 4;

    // ---------- prologue: stage kt=0 into buffer 0 ----------
#pragma unroll
    for (int c = 0; c < 3; ++c)
        gl_lds16(dsrc[c], &Bsh[0][(c * 256 + wud) * 8]);
    {
        uint4 xa = *(const uint4*)xp;   uint4 xb = *(const uint4*)(xp + 8);
        uint4 ga = *(const uint4*)gp_;  uint4 gb = *(const uint4*)(gp_ + 8);
        uint4 ba = *(const uint4*)bp_;  uint4 bb = *(const uint4*)(bp_ + 8);
        uint4 f0, f1;
        f0.x = fuse2(xa.x, ga.x, ba.x); f0.y = fuse2(xa.y, ga.y, ba.y);
        f0.z = fuse2(xa.z, ga.z, ba.z); f0.w = fuse2(xa.w, ga.w, ba.w);
        f1.x = fuse2(xb.x, gb.x, bb.x); f1.y = fuse2(xb.y, gb.y, bb.y);
        f1.z = fuse2(xb.z, gb.z, bb.z); f1.w = fuse2(xb.w, gb.w, bb.w);
        *(uint4*)&Ash[0][aw0] = f0; *(uint4*)&Ash[0][aw1] = f1;
    }
    __syncthreads();

    f32x4 acc[4][6] = {};
#pragma unroll 2
    for (int kt = 0; kt < 24; ++kt) {
        const int buf = kt & 1, nbf = buf ^ 1;
        uint4 xa, xb, ga, gb, ba, bb;
        if (kt < 23) {
            const int k0 = (kt + 1) * 32;
            // next-B DMA first (longest latency), then next-A loads
#pragma unroll
            for (int c = 0; c < 3; ++c)
                gl_lds16(dsrc[c] + k0, &Bsh[nbf][(c * 256 + wud) * 8]);
            xa = *(const uint4*)(xp + k0);  xb = *(const uint4*)(xp + k0 + 8);
            ga = *(const uint4*)(gp_ + k0); gb = *(const uint4*)(gp_ + k0 + 8);
            ba = *(const uint4*)(bp_ + k0); bb = *(const uint4*)(bp_ + k0 + 8);
        }

        ffrag af[4], bf[6];
#pragma unroll
        for (int mi = 0; mi < 4; ++mi)
            af[mi] = *reinterpret_cast<const ffrag*>(&Ash[buf][(quad * 128 + wm0 + mi * 16 + l15) * 8]);
#pragma unroll
        for (int ni = 0; ni < 6; ++ni)
            bf[ni] = *reinterpret_cast<const ffrag*>(&Bsh[buf][(quad * 192 + wn0 + ni * 16 + l15) * 8]);
#pragma unroll
        for (int mi = 0; mi < 4; ++mi)
#pragma unroll
            for (int ni = 0; ni < 6; ++ni)
                acc[mi][ni] = __builtin_amdgcn_mfma_f32_16x16x32_f16(af[mi], bf[ni], acc[mi][ni], 0, 0, 0);

        if (kt < 23) {
            uint4 f0, f1;
            f0.x = fuse2(xa.x, ga.x, ba.x); f0.y = fuse2(xa.y, ga.y, ba.y);
            f0.z = fuse2(xa.z, ga.z, ba.z); f0.w = fuse2(xa.w, ga.w, ba.w);
            f1.x = fuse2(xb.x, gb.x, bb.x); f1.y = fuse2(xb.y, gb.y, bb.y);
            f1.z = fuse2(xb.z, gb.z, bb.z); f1.w = fuse2(xb.w, gb.w, bb.w);
            *(uint4*)&Ash[nbf][aw0] = f0; *(uint4*)&Ash[nbf][aw1] = f1;
        }
        __syncthreads();
    }

    // epilogue: bias + tanh + store
#pragma unroll
    for (int mi = 0; mi < 4; ++mi)
#pragma unroll
        for (int ni = 0; ni < 6; ++ni) {
            int cg = nb * 192 + wn0 + ni * 16 + l15;
            int head = cg >> 7, m = cg & 127;
            float bv = biasc[cg];
#pragma unroll
            for (int reg = 0; reg < 4; ++reg) {
                int rg = wm0 + mi * 16 + quad * 4 + reg;
                out[((size_t)head * BP_ + row0 + rg) * M_ + m] = fast_tanh(acc[mi][ni][reg] + bv);
            }
        }
}

extern "C" void kernel_launch(void* const* d_in, const int* in_sizes, int n_in,
                              void* d_out, int out_size, void* d_ws, size_t ws_size,
                              hipStream_t stream)
{
    const float* seq     = (const float*)d_in[0];
    const float* gamma   = (const float*)d_in[1];
    const float* beta    = (const float*)d_in[2];
    const float* w_beta  = (const float*)d_in[3];
    const float* w_gamma = (const float*)d_in[4];
    const float* w_ent   = (const float*)d_in[5];
    const float* b_ent   = (const float*)d_in[6];
    const float* w_head  = (const float*)d_in[7];
    const float* b_head  = (const float*)d_in[8];
    const float* w_tail  = (const float*)d_in[9];
    const float* b_tail  = (const float*)d_in[10];
    float* out = (float*)d_out;

    // workspace layout (all 16B-aligned)
    char* ws = (char*)d_ws;
    h16* xn    = (h16*)ws; ws += (size_t)1024 * 768 * 2;  // normalized rows, f16
    h16* condb = (h16*)ws; ws += (size_t)1024 * 768 * 2;  // seq as f16
    h16* wgb   = (h16*)ws; ws += (size_t)768 * 768 * 2;   // w_gamma f16 [o][h]
    h16* wbb   = (h16*)ws; ws += (size_t)768 * 768 * 2;   // w_beta  f16 [o][h]
    h16* wct   = (h16*)ws; ws += (size_t)384 * 768 * 2;   // [n][h] combined ent|head|tail
    h16* gc    = (h16*)ws; ws += (size_t)1024 * 768 * 2;  // gamma_c f16
    h16* bc    = (h16*)ws; ws += (size_t)1024 * 768 * 2;  // beta_c  f16
    float* biasc = (float*)ws; ws += 384 * 4;             // [ent|head|tail] bias

    hipLaunchKernelGGL(k_prep, dim3(5763 + 1024), dim3(256), 0, stream,
                       seq, w_gamma, w_beta, w_ent, w_head, w_tail,
                       b_ent, b_head, b_tail, wgb, wbb, wct, biasc, xn, condb);
    hipLaunchKernelGGL(k_cond_gemm, dim3(16, 24), dim3(256), 0, stream,
                       condb, wgb, wbb, gamma, beta, gc, bc);
    hipLaunchKernelGGL(k_pair_gemm, dim3(516, 2), dim3(256), 0, stream,
                       xn, gc, bc, wct, biasc, out);
}